// Round 1
// baseline (2555.043 us; speedup 1.0000x reference)
//
#include <hip/hip_runtime.h>

// ---------------------------------------------------------------------------
// HeteroGAT (2 layers, 3 relations) on MI355X, fp32.
// Pipeline per call:
//   1. Build CSR (dst-sorted src lists) for each relation: hist -> scan -> scatter
//   2. Per relation-layer:
//        make_wa2 : Wsa = Wsrc·a_src (128x4), Wda = Wdst·a_dst (128x4)
//        gemv4    : es = Xs @ Wsa  [Ms,4],  ed = Xd @ Wda  [Md,4]
//        gemm_k128: hs = Xs @ Wsrc [Ms,128|64]
//        aggregate: wave-per-dst 2-pass softmax + weighted gather, fused
//                   bias/relation-sum/ReLU epilogue. No atomics.
// ---------------------------------------------------------------------------

#define NEG_SLOPE 0.2f

__global__ void hist_kernel(const int* __restrict__ dst, int E, int* __restrict__ counts) {
    int i = blockIdx.x * blockDim.x + threadIdx.x;
    if (i < E) atomicAdd(&counts[dst[i]], 1);
}

__global__ void scan_excl_kernel(const int* __restrict__ counts, int* __restrict__ rp, int N) {
    __shared__ int buf[2][1024];
    int t = threadIdx.x;
    int chunk = (N + 1023) >> 10;
    long b = (long)t * chunk;
    long e = b + chunk;
    if (b > N) b = N;
    if (e > N) e = N;
    int s = 0;
    for (long i = b; i < e; ++i) s += counts[i];
    buf[0][t] = s;
    __syncthreads();
    int cur = 0;
    for (int off = 1; off < 1024; off <<= 1) {
        int v = buf[cur][t];
        if (t >= off) v += buf[cur][t - off];
        buf[cur ^ 1][t] = v;
        cur ^= 1;
        __syncthreads();
    }
    int run = (t == 0) ? 0 : buf[cur][t - 1];
    for (long i = b; i < e; ++i) { rp[i] = run; run += counts[i]; }
    if (t == 1023) rp[N] = run;
}

__global__ void scatter_kernel(const int* __restrict__ src, const int* __restrict__ dst, int E,
                               const int* __restrict__ rp, int* __restrict__ cursor,
                               int* __restrict__ ss) {
    int i = blockIdx.x * blockDim.x + threadIdx.x;
    if (i < E) {
        int d = dst[i];
        int pos = rp[d] + atomicAdd(&cursor[d], 1);
        ss[pos] = src[i];
    }
}

// Collapse attention vectors into per-feature 128x4 matrices.
// threads 0..511 -> wsa (from Wsrc,a_src); 512..1023 -> wda (from Wdst,a_dst)
__global__ void make_wa2(const float* __restrict__ Ws, const float* __restrict__ as_,
                         const float* __restrict__ Wd, const float* __restrict__ ad_,
                         int Ncol, int C, float* __restrict__ wsa, float* __restrict__ wda) {
    int t = threadIdx.x;
    const float* W = (t < 512) ? Ws : Wd;
    const float* a = (t < 512) ? as_ : ad_;
    float* o       = (t < 512) ? wsa : wda;
    int tt = t & 511;
    int f = tt >> 2, h = tt & 3;
    float s = 0.f;
    for (int c = 0; c < C; ++c) s += W[f * Ncol + h * C + c] * a[h * C + c];
    o[f * 4 + h] = s;
}

// out[m, 0..3] = X[m, 0..127] @ Wc[128x4].  One wave per row.
__global__ void gemv4(const float* __restrict__ X, const float* __restrict__ Wc,
                      float* __restrict__ out, int M) {
    __shared__ float Ws[128 * 4];
    int tid = threadIdx.x;
    if (tid < 128) ((float4*)Ws)[tid] = ((const float4*)Wc)[tid];
    __syncthreads();
    int wid = blockIdx.x * 4 + (tid >> 6);
    if (wid >= M) return;
    int lane = tid & 63;
    const float* xr = X + (size_t)wid * 128;
    float x0 = xr[lane], x1 = xr[lane + 64];
    float4 w0 = *(const float4*)(Ws + lane * 4);
    float4 w1 = *(const float4*)(Ws + (lane + 64) * 4);
    float4 p;
    p.x = x0 * w0.x + x1 * w1.x;
    p.y = x0 * w0.y + x1 * w1.y;
    p.z = x0 * w0.z + x1 * w1.z;
    p.w = x0 * w0.w + x1 * w1.w;
#pragma unroll
    for (int off = 32; off; off >>= 1) {
        p.x += __shfl_xor(p.x, off);
        p.y += __shfl_xor(p.y, off);
        p.z += __shfl_xor(p.z, off);
        p.w += __shfl_xor(p.w, off);
    }
    if (lane == 0) *(float4*)(out + (size_t)wid * 4) = p;
}

// C[M,BN] = A[M,128] @ W[128,BN].  32-row tile/block, W staged in two 64-row
// K-chunks (keeps LDS <= 48KB -> 3 blocks/CU).
template <int BN>
__launch_bounds__(256)
__global__ void gemm_k128(const float* __restrict__ A, const float* __restrict__ W,
                          float* __restrict__ C, int M) {
    __shared__ float Ws[64 * BN];
    __shared__ float As[32 * 128];
    const int tid = threadIdx.x;
    const int row0 = blockIdx.x * 32;
    const int maxr = M - row0;
    {
        const float4* A4 = (const float4*)(A + (size_t)row0 * 128);
        float4* As4 = (float4*)As;
#pragma unroll
        for (int i = 0; i < 4; ++i) {
            int idx = i * 256 + tid;
            int r = idx >> 5;  // 32 float4 per row
            float4 v = make_float4(0.f, 0.f, 0.f, 0.f);
            if (r < maxr) v = A4[idx];
            As4[idx] = v;
        }
    }
    constexpr int CG = BN / 4;        // col groups of 4
    constexpr int RPT = 32 / (256 / CG);  // rows per thread (4 for BN=128, 2 for BN=64)
    const int tx = tid % CG, ty = tid / CG;
    float acc[RPT][4];
#pragma unroll
    for (int r = 0; r < RPT; ++r) acc[r][0] = acc[r][1] = acc[r][2] = acc[r][3] = 0.f;
    const float* Ap = As + ty * RPT * 128;
    const float* Wp = Ws + tx * 4;

    for (int half = 0; half < 2; ++half) {
        const float4* W4 = (const float4*)(W + half * 64 * BN);
        float4* Ws4 = (float4*)Ws;
        constexpr int WTOT = 64 * BN / 4;
        for (int i = tid; i < WTOT; i += 256) Ws4[i] = W4[i];
        __syncthreads();
        const int kbase = half * 64;
        for (int kk = 0; kk < 64; kk += 4) {
            float4 w0 = *(const float4*)(Wp + (kk + 0) * BN);
            float4 w1 = *(const float4*)(Wp + (kk + 1) * BN);
            float4 w2 = *(const float4*)(Wp + (kk + 2) * BN);
            float4 w3 = *(const float4*)(Wp + (kk + 3) * BN);
#pragma unroll
            for (int r = 0; r < RPT; ++r) {
                float4 a = *(const float4*)(Ap + r * 128 + kbase + kk);
                acc[r][0] += a.x * w0.x + a.y * w1.x + a.z * w2.x + a.w * w3.x;
                acc[r][1] += a.x * w0.y + a.y * w1.y + a.z * w2.y + a.w * w3.y;
                acc[r][2] += a.x * w0.z + a.y * w1.z + a.z * w2.z + a.w * w3.z;
                acc[r][3] += a.x * w0.w + a.y * w1.w + a.z * w2.w + a.w * w3.w;
            }
        }
        __syncthreads();
    }
#pragma unroll
    for (int r = 0; r < RPT; ++r) {
        int row = ty * RPT + r;
        if (row < maxr)
            *(float4*)(C + (size_t)(row0 + row) * BN + tx * 4) =
                make_float4(acc[r][0], acc[r][1], acc[r][2], acc[r][3]);
    }
}

// One wave per dst node. mode: bit0 = relu, bit1 = add-to-existing.
// 0=WRITE 1=WRITE_RELU 2=ADD 3=ADD_RELU
template <int CH>  // 128 (layer1) or 64 (layer2); H=4 heads
__launch_bounds__(256)
__global__ void aggregate(const int* __restrict__ rp, const int* __restrict__ ss,
                          const float* __restrict__ hs, const float* __restrict__ es,
                          const float* __restrict__ ed, const float* __restrict__ bias,
                          float* __restrict__ out, int Ndst, int mode) {
    int wid = blockIdx.x * 4 + (threadIdx.x >> 6);
    if (wid >= Ndst) return;
    int lane = threadIdx.x & 63;
    int h = lane >> 4;
    int beg = rp[wid], end = rp[wid + 1];
    float4 edv = *(const float4*)(ed + (size_t)wid * 4);

    // pass 1: per-head max over all incoming edges
    float m0 = -1e30f, m1 = -1e30f, m2 = -1e30f, m3 = -1e30f;
    for (int i = beg + lane; i < end; i += 64) {
        int s = ss[i];
        float4 ev = *(const float4*)(es + (size_t)s * 4);
        float e0 = ev.x + edv.x; e0 = e0 > 0.f ? e0 : NEG_SLOPE * e0;
        float e1 = ev.y + edv.y; e1 = e1 > 0.f ? e1 : NEG_SLOPE * e1;
        float e2 = ev.z + edv.z; e2 = e2 > 0.f ? e2 : NEG_SLOPE * e2;
        float e3 = ev.w + edv.w; e3 = e3 > 0.f ? e3 : NEG_SLOPE * e3;
        m0 = fmaxf(m0, e0); m1 = fmaxf(m1, e1); m2 = fmaxf(m2, e2); m3 = fmaxf(m3, e3);
    }
#pragma unroll
    for (int off = 32; off; off >>= 1) {
        m0 = fmaxf(m0, __shfl_xor(m0, off));
        m1 = fmaxf(m1, __shfl_xor(m1, off));
        m2 = fmaxf(m2, __shfl_xor(m2, off));
        m3 = fmaxf(m3, __shfl_xor(m3, off));
    }
    float mh  = (h == 0) ? m0 : (h == 1) ? m1 : (h == 2) ? m2 : m3;
    float edh = (h == 0) ? edv.x : (h == 1) ? edv.y : (h == 2) ? edv.z : edv.w;

    // pass 2: weighted accumulate, lanes = channels
    float acc0 = 0.f, acc1 = 0.f, den = 0.f;
    for (int i = beg; i < end; ++i) {
        int s = ss[i];
        float e = es[(size_t)s * 4 + h] + edh;
        e = e > 0.f ? e : NEG_SLOPE * e;
        float w = __expf(e - mh);
        den += w;
        if constexpr (CH == 128) {
            float2 v = *(const float2*)(hs + (size_t)s * 128 + lane * 2);
            acc0 += w * v.x;
            acc1 += w * v.y;
        } else {
            acc0 += w * hs[(size_t)s * 64 + lane];
        }
    }
    float inv = 1.0f / (den + 1e-16f);
    if constexpr (CH == 128) {
        size_t i0 = (size_t)wid * 128 + lane * 2;
        float2 bv = *(const float2*)(bias + lane * 2);
        float o0 = acc0 * inv + bv.x;
        float o1 = acc1 * inv + bv.y;
        if (mode & 2) { o0 += out[i0]; o1 += out[i0 + 1]; }
        if (mode & 1) { o0 = fmaxf(o0, 0.f); o1 = fmaxf(o1, 0.f); }
        *(float2*)(out + i0) = make_float2(o0, o1);
    } else {
        size_t i0 = (size_t)wid * 64 + lane;
        float o0 = acc0 * inv + bias[lane];
        if (mode & 2) o0 += out[i0];
        if (mode & 1) o0 = fmaxf(o0, 0.f);
        out[i0] = o0;
    }
}

extern "C" void kernel_launch(void* const* d_in, const int* in_sizes, int n_in,
                              void* d_out, int out_size, void* d_ws, size_t ws_size,
                              hipStream_t stream) {
    const float* xp     = (const float*)d_in[0];
    const float* xa     = (const float*)d_in[1];
    const int* src_pp   = (const int*)d_in[2];
    const int* dst_pp   = (const int*)d_in[3];
    const int* src_ap   = (const int*)d_in[4];
    const int* dst_ap   = (const int*)d_in[5];
    const int* src_pa   = (const int*)d_in[6];
    const int* dst_pa   = (const int*)d_in[7];
    const float* Wsrc1  = (const float*)d_in[8];
    const float* Wdst1  = (const float*)d_in[9];
    const float* asrc1  = (const float*)d_in[10];
    const float* adst1  = (const float*)d_in[11];
    const float* b1     = (const float*)d_in[12];
    const float* Wsrc2  = (const float*)d_in[13];
    const float* Wdst2  = (const float*)d_in[14];
    const float* asrc2  = (const float*)d_in[15];
    const float* adst2  = (const float*)d_in[16];
    const float* b2     = (const float*)d_in[17];

    const int NP  = in_sizes[0] / 128;
    const int NA  = in_sizes[1] / 128;
    const int Epp = in_sizes[2];
    const int Eap = in_sizes[4];
    const int Epa = in_sizes[6];

    char* w = (char*)d_ws;
    auto alloc = [&](size_t bytes) {
        char* p = w;
        w += (bytes + 255) & ~(size_t)255;
        return p;
    };
    float* P1    = (float*)alloc((size_t)NP * 128 * 4);  // hs buffer (paper src)
    float* A1    = (float*)alloc((size_t)NA * 128 * 4);  // hs buffer (author src)
    float* HP    = (float*)alloc((size_t)NP * 128 * 4);  // layer-1 paper out
    float* HA    = (float*)alloc((size_t)NA * 128 * 4);  // layer-1 author out
    float* ES    = (float*)alloc((size_t)NP * 4 * 4);
    float* ED    = (float*)alloc((size_t)NP * 4 * 4);
    float* WSA   = (float*)alloc(512 * 4);
    float* WDA   = (float*)alloc(512 * 4);
    int* counts  = (int*)alloc((size_t)NP * 4);
    int* rp_pp   = (int*)alloc((size_t)(NP + 1) * 4);
    int* rp_ap   = (int*)alloc((size_t)(NP + 1) * 4);
    int* rp_pa   = (int*)alloc((size_t)(NA + 1) * 4);
    int* ss_pp   = (int*)alloc((size_t)Epp * 4);
    int* ss_ap   = (int*)alloc((size_t)Eap * 4);
    int* ss_pa   = (int*)alloc((size_t)Epa * 4);

    auto build_csr = [&](const int* src, const int* dst, int E, int Nd, int* rp, int* ss) {
        hipMemsetAsync(counts, 0, (size_t)Nd * 4, stream);
        hist_kernel<<<(E + 255) / 256, 256, 0, stream>>>(dst, E, counts);
        scan_excl_kernel<<<1, 1024, 0, stream>>>(counts, rp, Nd);
        hipMemsetAsync(counts, 0, (size_t)Nd * 4, stream);
        scatter_kernel<<<(E + 255) / 256, 256, 0, stream>>>(src, dst, E, rp, counts, ss);
    };
    build_csr(src_pp, dst_pp, Epp, NP, rp_pp, ss_pp);
    build_csr(src_ap, dst_ap, Eap, NP, rp_ap, ss_ap);
    build_csr(src_pa, dst_pa, Epa, NA, rp_pa, ss_pa);

    auto do_rel = [&](const float* Xs, int Ms, const float* Xd, int Md,
                      const float* Wsrc, const float* as_, const float* Wdst, const float* ad_,
                      const float* bias, int Ncol, int C, const int* rp, const int* ss,
                      float* hsbuf, float* outp, int mode) {
        make_wa2<<<1, 1024, 0, stream>>>(Wsrc, as_, Wdst, ad_, Ncol, C, WSA, WDA);
        gemv4<<<(Ms + 3) / 4, 256, 0, stream>>>(Xs, WSA, ES, Ms);
        gemv4<<<(Md + 3) / 4, 256, 0, stream>>>(Xd, WDA, ED, Md);
        if (Ncol == 128) {
            gemm_k128<128><<<(Ms + 31) / 32, 256, 0, stream>>>(Xs, Wsrc, hsbuf, Ms);
            aggregate<128><<<(Md + 3) / 4, 256, 0, stream>>>(rp, ss, hsbuf, ES, ED, bias,
                                                             outp, Md, mode);
        } else {
            gemm_k128<64><<<(Ms + 31) / 32, 256, 0, stream>>>(Xs, Wsrc, hsbuf, Ms);
            aggregate<64><<<(Md + 3) / 4, 256, 0, stream>>>(rp, ss, hsbuf, ES, ED, bias,
                                                            outp, Md, mode);
        }
    };

    // ---- Layer 1 ----
    // pa (r=2): paper -> author, write+relu into HA
    do_rel(xp, NP, xa, NA, Wsrc1 + 2 * 16384, asrc1 + 2 * 128, Wdst1 + 2 * 16384,
           adst1 + 2 * 128, b1 + 2 * 128, 128, 32, rp_pa, ss_pa, P1, HA, 1);
    // pp (r=0): paper -> paper, write into HP
    do_rel(xp, NP, xp, NP, Wsrc1, asrc1, Wdst1, adst1, b1,
           128, 32, rp_pp, ss_pp, P1, HP, 0);
    // ap (r=1): author -> paper, add+relu into HP
    do_rel(xa, NA, xp, NP, Wsrc1 + 1 * 16384, asrc1 + 1 * 128, Wdst1 + 1 * 16384,
           adst1 + 1 * 128, b1 + 1 * 128, 128, 32, rp_ap, ss_ap, A1, HP, 3);

    float* Opap = (float*)d_out;
    float* Oaut = (float*)d_out + (size_t)NP * 64;

    // ---- Layer 2 ----
    // pa (r=2): write into author output
    do_rel(HP, NP, HA, NA, Wsrc2 + 2 * 8192, asrc2 + 2 * 64, Wdst2 + 2 * 8192,
           adst2 + 2 * 64, b2 + 2 * 64, 64, 16, rp_pa, ss_pa, P1, Oaut, 0);
    // pp (r=0): write into paper output
    do_rel(HP, NP, HP, NP, Wsrc2, asrc2, Wdst2, adst2, b2,
           64, 16, rp_pp, ss_pp, P1, Opap, 0);
    // ap (r=1): add into paper output
    do_rel(HA, NA, HP, NP, Wsrc2 + 1 * 8192, asrc2 + 1 * 64, Wdst2 + 1 * 8192,
           adst2 + 1 * 64, b2 + 1 * 64, 64, 16, rp_ap, ss_ap, A1, Opap, 2);
}

// Round 2
// 1476.225 us; speedup vs baseline: 1.7308x; 1.7308x over previous
//
#include <hip/hip_runtime.h>

// ---------------------------------------------------------------------------
// HeteroGAT (2 layers, 3 relations) on MI355X, fp32.
//   1. CSR build (fused across the 3 relations): hist3 -> scan3 -> scatter3
//   2. Per relation-layer:
//        make_wda : Wda = Wdst·a_dst (128x4)
//        gemv4    : ed = Xd @ Wda  [Md,4]
//        gemm_es  : hs = Xs @ Wsrc [Ms,BN]  + fused es = (hs·a_src) epilogue
//        aggregate: wave-per-dst softmax+gather, chunk-16 register-resident
//                   weights, unrolled gather loop. No atomics.
// ---------------------------------------------------------------------------

__global__ void hist3(const int* __restrict__ d0, int E0, const int* __restrict__ d1, int E1,
                      const int* __restrict__ d2, int E2,
                      int* __restrict__ c0, int* __restrict__ c1, int* __restrict__ c2) {
    int i = blockIdx.x * blockDim.x + threadIdx.x;
    if (i < E0) atomicAdd(&c0[d0[i]], 1);
    if (i < E1) atomicAdd(&c1[d1[i]], 1);
    if (i < E2) atomicAdd(&c2[d2[i]], 1);
}

__global__ void scan3(const int* __restrict__ c0, int* __restrict__ r0, int N0,
                      const int* __restrict__ c1, int* __restrict__ r1, int N1,
                      const int* __restrict__ c2, int* __restrict__ r2, int N2) {
    __shared__ int buf[2][1024];
    const int* counts = (blockIdx.x == 0) ? c0 : (blockIdx.x == 1) ? c1 : c2;
    int* rp           = (blockIdx.x == 0) ? r0 : (blockIdx.x == 1) ? r1 : r2;
    int N             = (blockIdx.x == 0) ? N0 : (blockIdx.x == 1) ? N1 : N2;
    int t = threadIdx.x;
    int chunk = (N + 1023) >> 10;
    long b = (long)t * chunk;
    long e = b + chunk;
    if (b > N) b = N;
    if (e > N) e = N;
    int s = 0;
    for (long i = b; i < e; ++i) s += counts[i];
    buf[0][t] = s;
    __syncthreads();
    int cur = 0;
    for (int off = 1; off < 1024; off <<= 1) {
        int v = buf[cur][t];
        if (t >= off) v += buf[cur][t - off];
        buf[cur ^ 1][t] = v;
        cur ^= 1;
        __syncthreads();
    }
    int run = (t == 0) ? 0 : buf[cur][t - 1];
    for (long i = b; i < e; ++i) { rp[i] = run; run += counts[i]; }
    if (t == 1023) rp[N] = run;
}

__global__ void scatter3(const int* __restrict__ s0, const int* __restrict__ d0, int E0,
                         const int* __restrict__ rp0, int* __restrict__ cu0, int* __restrict__ ss0,
                         const int* __restrict__ s1, const int* __restrict__ d1, int E1,
                         const int* __restrict__ rp1, int* __restrict__ cu1, int* __restrict__ ss1,
                         const int* __restrict__ s2, const int* __restrict__ d2, int E2,
                         const int* __restrict__ rp2, int* __restrict__ cu2, int* __restrict__ ss2) {
    int i = blockIdx.x * blockDim.x + threadIdx.x;
    if (i < E0) { int d = d0[i]; ss0[rp0[d] + atomicAdd(&cu0[d], 1)] = s0[i]; }
    if (i < E1) { int d = d1[i]; ss1[rp1[d] + atomicAdd(&cu1[d], 1)] = s1[i]; }
    if (i < E2) { int d = d2[i]; ss2[rp2[d] + atomicAdd(&cu2[d], 1)] = s2[i]; }
}

// Wda[f,h] = sum_c Wd[f, h*C+c] * ad[h*C+c]   (f<128, h<4), 512 threads
__global__ void make_wda(const float* __restrict__ Wd, const float* __restrict__ ad,
                         int Ncol, int C, float* __restrict__ wda) {
    int t = threadIdx.x;
    int f = t >> 2, h = t & 3;
    float s = 0.f;
    for (int c = 0; c < C; ++c) s += Wd[f * Ncol + h * C + c] * ad[h * C + c];
    wda[f * 4 + h] = s;
}

// out[m, 0..3] = X[m, 0..127] @ Wc[128x4].  One wave per row.
__global__ void gemv4(const float* __restrict__ X, const float* __restrict__ Wc,
                      float* __restrict__ out, int M) {
    __shared__ float Ws[128 * 4];
    int tid = threadIdx.x;
    if (tid < 128) ((float4*)Ws)[tid] = ((const float4*)Wc)[tid];
    __syncthreads();
    int wid = blockIdx.x * 4 + (tid >> 6);
    if (wid >= M) return;
    int lane = tid & 63;
    const float* xr = X + (size_t)wid * 128;
    float x0 = xr[lane], x1 = xr[lane + 64];
    float4 w0 = *(const float4*)(Ws + lane * 4);
    float4 w1 = *(const float4*)(Ws + (lane + 64) * 4);
    float4 p;
    p.x = x0 * w0.x + x1 * w1.x;
    p.y = x0 * w0.y + x1 * w1.y;
    p.z = x0 * w0.z + x1 * w1.z;
    p.w = x0 * w0.w + x1 * w1.w;
#pragma unroll
    for (int off = 32; off; off >>= 1) {
        p.x += __shfl_xor(p.x, off);
        p.y += __shfl_xor(p.y, off);
        p.z += __shfl_xor(p.z, off);
        p.w += __shfl_xor(p.w, off);
    }
    if (lane == 0) *(float4*)(out + (size_t)wid * 4) = p;
}

// C[M,BN] = A[M,128] @ W[128,BN], plus fused es[m,h] = sum_c C[m,h*C+c]*a_s[h*C+c].
// 64-row tile, KC=32 K-chunks, 8x4 (BN=128) / 4x4 (BN=64) register micro-tile.
template <int BN>
__launch_bounds__(256)
__global__ void gemm_es(const float* __restrict__ A, const float* __restrict__ W,
                        const float* __restrict__ a_s,
                        float* __restrict__ C, float* __restrict__ es, int M) {
    constexpr int KC = 32;
    constexpr int CG = BN / 4;       // threads covering columns: 32 or 16
    constexpr int RPT = CG / 4;      // rows per thread: 8 or 4
    __shared__ float As[64 * KC];    // [row][k] within chunk
    __shared__ float Ws[KC * BN];    // [k][n]
    const int tid = threadIdx.x;
    const int tx = tid % CG, ty = tid / CG;
    const int row0 = blockIdx.x * 64;
    const int maxr = M - row0;

    float acc[RPT][4];
#pragma unroll
    for (int r = 0; r < RPT; ++r) acc[r][0] = acc[r][1] = acc[r][2] = acc[r][3] = 0.f;

    for (int kc = 0; kc < 128; kc += KC) {
        // stage A chunk: 64 rows x 32 k = 512 float4, 2 per thread
        const float4* A4 = (const float4*)A;
        float4* As4 = (float4*)As;
#pragma unroll
        for (int c = 0; c < 2; ++c) {
            int idx = c * 256 + tid;
            int row = idx >> 3, kq = idx & 7;
            float4 v = make_float4(0.f, 0.f, 0.f, 0.f);
            if (row < maxr) v = A4[(size_t)(row0 + row) * 32 + (kc >> 2) + kq];
            As4[idx] = v;
        }
        // stage W chunk: KC x BN
        {
            const float4* W4 = (const float4*)(W + kc * BN);
            float4* Ws4 = (float4*)Ws;
#pragma unroll
            for (int c = 0; c < KC * BN / 4 / 256; ++c) Ws4[c * 256 + tid] = W4[c * 256 + tid];
        }
        __syncthreads();
#pragma unroll 2
        for (int kk = 0; kk < KC; kk += 4) {
            float4 w0 = *(const float4*)(Ws + (kk + 0) * BN + tx * 4);
            float4 w1 = *(const float4*)(Ws + (kk + 1) * BN + tx * 4);
            float4 w2 = *(const float4*)(Ws + (kk + 2) * BN + tx * 4);
            float4 w3 = *(const float4*)(Ws + (kk + 3) * BN + tx * 4);
#pragma unroll
            for (int r = 0; r < RPT; ++r) {
                float4 a = *(const float4*)(As + (ty * RPT + r) * KC + kk);
                acc[r][0] += a.x * w0.x + a.y * w1.x + a.z * w2.x + a.w * w3.x;
                acc[r][1] += a.x * w0.y + a.y * w1.y + a.z * w2.y + a.w * w3.y;
                acc[r][2] += a.x * w0.z + a.y * w1.z + a.z * w2.z + a.w * w3.z;
                acc[r][3] += a.x * w0.w + a.y * w1.w + a.z * w2.w + a.w * w3.w;
            }
        }
        __syncthreads();
    }

    // epilogue: store hs + fused es reduction
    float4 av = *(const float4*)(a_s + tx * 4);
    constexpr int G = CG / 4;  // threads per head group: 8 (C=32) or 4 (C=16)
#pragma unroll
    for (int r = 0; r < RPT; ++r) {
        int row = ty * RPT + r;
        bool ok = row < maxr;
        if (ok)
            *(float4*)(C + (size_t)(row0 + row) * BN + tx * 4) =
                make_float4(acc[r][0], acc[r][1], acc[r][2], acc[r][3]);
        float p = acc[r][0] * av.x + acc[r][1] * av.y + acc[r][2] * av.z + acc[r][3] * av.w;
#pragma unroll
        for (int off = 1; off < G; off <<= 1) p += __shfl_xor(p, off);
        if (ok && (tx % G) == 0) es[(size_t)(row0 + row) * 4 + tx / G] = p;
    }
}

// One wave per dst node. Chunk-16 edge processing: lane = (head h, edge el).
// mode: bit0 = relu, bit1 = add-to-existing.
template <int CH>  // 128 (layer1) or 64 (layer2); H=4 heads
__launch_bounds__(256)
__global__ void aggregate(const int* __restrict__ rp, const int* __restrict__ ss,
                          const float* __restrict__ hs, const float* __restrict__ es,
                          const float* __restrict__ ed, const float* __restrict__ bias,
                          float* __restrict__ out, int Ndst, int mode) {
    int wid = blockIdx.x * 4 + (threadIdx.x >> 6);
    if (wid >= Ndst) return;
    int lane = threadIdx.x & 63;
    int h = lane >> 4, el = lane & 15;
    int beg = rp[wid], end = rp[wid + 1];
    float edh = ed[wid * 4 + h];

    // pass 1: per-head max (lane covers edge el of each 16-chunk at head h)
    float m = -3e38f, e_c = -3e38f;
    int s_c = 0;
    for (int base = beg; base < end; base += 16) {
        int idx = base + el;
        int s = 0;
        float e = -3e38f;
        if (idx < end) {
            s = ss[idx];
            e = es[s * 4 + h] + edh;
            e = e > 0.f ? e : 0.2f * e;
        }
        if (base == beg) { s_c = s; e_c = e; }
        m = fmaxf(m, e);
    }
#pragma unroll
    for (int off = 1; off < 16; off <<= 1) m = fmaxf(m, __shfl_xor(m, off));

    // pass 2: softmax weights in registers, unrolled gather
    float acc0 = 0.f, acc1 = 0.f, den = 0.f;
    for (int base = beg; base < end; base += 16) {
        int n = end - base;
        if (n > 16) n = 16;
        int s;
        float e;
        if (base == beg) { s = s_c; e = e_c; }
        else {
            int idx = base + el;
            s = 0; e = -3e38f;
            if (idx < end) {
                s = ss[idx];
                e = es[s * 4 + h] + edh;
                e = e > 0.f ? e : 0.2f * e;
            }
        }
        float w = (el < n) ? __expf(e - m) : 0.f;
        int j = 0;
        for (; j + 4 <= n; j += 4) {
            int s0 = __shfl(s, j), s1 = __shfl(s, j + 1), s2 = __shfl(s, j + 2), s3 = __shfl(s, j + 3);
            float w0 = __shfl(w, (h << 4) | j);
            float w1 = __shfl(w, (h << 4) | (j + 1));
            float w2 = __shfl(w, (h << 4) | (j + 2));
            float w3 = __shfl(w, (h << 4) | (j + 3));
            if constexpr (CH == 128) {
                float2 v0 = *(const float2*)(hs + s0 * 128 + lane * 2);
                float2 v1 = *(const float2*)(hs + s1 * 128 + lane * 2);
                float2 v2 = *(const float2*)(hs + s2 * 128 + lane * 2);
                float2 v3 = *(const float2*)(hs + s3 * 128 + lane * 2);
                acc0 += w0 * v0.x + w1 * v1.x + w2 * v2.x + w3 * v3.x;
                acc1 += w0 * v0.y + w1 * v1.y + w2 * v2.y + w3 * v3.y;
            } else {
                float v0 = hs[s0 * 64 + lane];
                float v1 = hs[s1 * 64 + lane];
                float v2 = hs[s2 * 64 + lane];
                float v3 = hs[s3 * 64 + lane];
                acc0 += w0 * v0 + w1 * v1 + w2 * v2 + w3 * v3;
            }
            den += w0 + w1 + w2 + w3;
        }
        for (; j < n; ++j) {
            int sj = __shfl(s, j);
            float wj = __shfl(w, (h << 4) | j);
            if constexpr (CH == 128) {
                float2 v = *(const float2*)(hs + sj * 128 + lane * 2);
                acc0 += wj * v.x;
                acc1 += wj * v.y;
            } else {
                acc0 += wj * hs[sj * 64 + lane];
            }
            den += wj;
        }
    }
    float inv = 1.0f / (den + 1e-16f);
    if constexpr (CH == 128) {
        size_t i0 = (size_t)wid * 128 + lane * 2;
        float2 bv = *(const float2*)(bias + lane * 2);
        float o0 = acc0 * inv + bv.x;
        float o1 = acc1 * inv + bv.y;
        if (mode & 2) { o0 += out[i0]; o1 += out[i0 + 1]; }
        if (mode & 1) { o0 = fmaxf(o0, 0.f); o1 = fmaxf(o1, 0.f); }
        *(float2*)(out + i0) = make_float2(o0, o1);
    } else {
        size_t i0 = (size_t)wid * 64 + lane;
        float o0 = acc0 * inv + bias[lane];
        if (mode & 2) o0 += out[i0];
        if (mode & 1) o0 = fmaxf(o0, 0.f);
        out[i0] = o0;
    }
}

extern "C" void kernel_launch(void* const* d_in, const int* in_sizes, int n_in,
                              void* d_out, int out_size, void* d_ws, size_t ws_size,
                              hipStream_t stream) {
    const float* xp     = (const float*)d_in[0];
    const float* xa     = (const float*)d_in[1];
    const int* src_pp   = (const int*)d_in[2];
    const int* dst_pp   = (const int*)d_in[3];
    const int* src_ap   = (const int*)d_in[4];
    const int* dst_ap   = (const int*)d_in[5];
    const int* src_pa   = (const int*)d_in[6];
    const int* dst_pa   = (const int*)d_in[7];
    const float* Wsrc1  = (const float*)d_in[8];
    const float* Wdst1  = (const float*)d_in[9];
    const float* asrc1  = (const float*)d_in[10];
    const float* adst1  = (const float*)d_in[11];
    const float* b1     = (const float*)d_in[12];
    const float* Wsrc2  = (const float*)d_in[13];
    const float* Wdst2  = (const float*)d_in[14];
    const float* asrc2  = (const float*)d_in[15];
    const float* adst2  = (const float*)d_in[16];
    const float* b2     = (const float*)d_in[17];

    const int NP  = in_sizes[0] / 128;
    const int NA  = in_sizes[1] / 128;
    const int Epp = in_sizes[2];
    const int Eap = in_sizes[4];
    const int Epa = in_sizes[6];

    char* w = (char*)d_ws;
    auto alloc = [&](size_t bytes) {
        char* p = w;
        w += (bytes + 255) & ~(size_t)255;
        return p;
    };
    float* P1    = (float*)alloc((size_t)NP * 128 * 4);
    float* A1    = (float*)alloc((size_t)NA * 128 * 4);
    float* HP    = (float*)alloc((size_t)NP * 128 * 4);
    float* HA    = (float*)alloc((size_t)NA * 128 * 4);
    float* ES    = (float*)alloc((size_t)NP * 4 * 4);
    float* ED    = (float*)alloc((size_t)NP * 4 * 4);
    float* WDA   = (float*)alloc(512 * 4);
    int* c_pp    = (int*)alloc((size_t)NP * 4);
    int* c_ap    = (int*)alloc((size_t)NP * 4);
    int* c_pa    = (int*)alloc((size_t)NA * 4);
    int* rp_pp   = (int*)alloc((size_t)(NP + 1) * 4);
    int* rp_ap   = (int*)alloc((size_t)(NP + 1) * 4);
    int* rp_pa   = (int*)alloc((size_t)(NA + 1) * 4);
    int* ss_pp   = (int*)alloc((size_t)Epp * 4);
    int* ss_ap   = (int*)alloc((size_t)Eap * 4);
    int* ss_pa   = (int*)alloc((size_t)Epa * 4);

    // counts are contiguous: one memset covers all three
    size_t counts_bytes = ((size_t)NP * 4 + 255 & ~(size_t)255) +
                          ((size_t)NP * 4 + 255 & ~(size_t)255) +
                          ((size_t)NA * 4 + 255 & ~(size_t)255);
    int Emax = Epp > Eap ? Epp : Eap;
    if (Epa > Emax) Emax = Epa;

    hipMemsetAsync(c_pp, 0, counts_bytes, stream);
    hist3<<<(Emax + 255) / 256, 256, 0, stream>>>(dst_pp, Epp, dst_ap, Eap, dst_pa, Epa,
                                                  c_pp, c_ap, c_pa);
    scan3<<<3, 1024, 0, stream>>>(c_pp, rp_pp, NP, c_ap, rp_ap, NP, c_pa, rp_pa, NA);
    hipMemsetAsync(c_pp, 0, counts_bytes, stream);
    scatter3<<<(Emax + 255) / 256, 256, 0, stream>>>(
        src_pp, dst_pp, Epp, rp_pp, c_pp, ss_pp,
        src_ap, dst_ap, Eap, rp_ap, c_ap, ss_ap,
        src_pa, dst_pa, Epa, rp_pa, c_pa, ss_pa);

    auto do_rel = [&](const float* Xs, int Ms, const float* Xd, int Md,
                      const float* Wsrc, const float* as_, const float* Wdst, const float* ad_,
                      const float* bias, int Ncol, int C, const int* rp, const int* ss,
                      float* hsbuf, float* outp, int mode) {
        make_wda<<<1, 512, 0, stream>>>(Wdst, ad_, Ncol, C, WDA);
        gemv4<<<(Md + 3) / 4, 256, 0, stream>>>(Xd, WDA, ED, Md);
        if (Ncol == 128) {
            gemm_es<128><<<(Ms + 63) / 64, 256, 0, stream>>>(Xs, Wsrc, as_, hsbuf, ES, Ms);
            aggregate<128><<<(Md + 3) / 4, 256, 0, stream>>>(rp, ss, hsbuf, ES, ED, bias,
                                                             outp, Md, mode);
        } else {
            gemm_es<64><<<(Ms + 63) / 64, 256, 0, stream>>>(Xs, Wsrc, as_, hsbuf, ES, Ms);
            aggregate<64><<<(Md + 3) / 4, 256, 0, stream>>>(rp, ss, hsbuf, ES, ED, bias,
                                                            outp, Md, mode);
        }
    };

    // ---- Layer 1 ----
    do_rel(xp, NP, xa, NA, Wsrc1 + 2 * 16384, asrc1 + 2 * 128, Wdst1 + 2 * 16384,
           adst1 + 2 * 128, b1 + 2 * 128, 128, 32, rp_pa, ss_pa, P1, HA, 1);
    do_rel(xp, NP, xp, NP, Wsrc1, asrc1, Wdst1, adst1, b1,
           128, 32, rp_pp, ss_pp, P1, HP, 0);
    do_rel(xa, NA, xp, NP, Wsrc1 + 1 * 16384, asrc1 + 1 * 128, Wdst1 + 1 * 16384,
           adst1 + 1 * 128, b1 + 1 * 128, 128, 32, rp_ap, ss_ap, A1, HP, 3);

    float* Opap = (float*)d_out;
    float* Oaut = (float*)d_out + (size_t)NP * 64;

    // ---- Layer 2 ---- (input dim 128 -> Ncol=64, C=16)
    do_rel(HP, NP, HA, NA, Wsrc2 + 2 * 8192, asrc2 + 2 * 64, Wdst2 + 2 * 8192,
           adst2 + 2 * 64, b2 + 2 * 64, 64, 16, rp_pa, ss_pa, P1, Oaut, 0);
    do_rel(HP, NP, HP, NP, Wsrc2, asrc2, Wdst2, adst2, b2,
           64, 16, rp_pp, ss_pp, P1, Opap, 0);
    do_rel(HA, NA, HP, NP, Wsrc2 + 1 * 8192, asrc2 + 1 * 64, Wdst2 + 1 * 8192,
           adst2 + 1 * 64, b2 + 1 * 64, 64, 16, rp_ap, ss_ap, A1, Opap, 2);
}